// Round 10
// baseline (296.631 us; speedup 1.0000x reference)
//
#include <hip/hip_runtime.h>
#include <hip/hip_bf16.h>

typedef __hip_bfloat16 bf16;

static constexpr int N_NODES = 100000;
static constexpr int N_EDGES = 3200000;
static constexpr int F_IN    = 54;
static constexpr int F_HID   = 16;

// bucket/CSR path
static constexpr int BSHIFT    = 7;                  // 128 nodes per bucket
static constexpr int BNODES    = 128;
static constexpr int NBUCK     = (N_NODES + BNODES - 1) / BNODES;  // 782
static constexpr int CAP_B     = 5120;
static constexpr int BIN_CHUNK = 8192;
static constexpr int GRDB      = (N_EDGES + BIN_CHUNK - 1) / BIN_CHUNK;  // 391
static constexpr int GRDN_F    = (N_NODES + 1023) / 1024;                // 98

// ---------------------------------------------------------------------------
// ws layout (float indices). Bucket end = 41,634,832 B (< proven 52.4 MB).
// h1/h2 stored as bf16 (32 B rows -> 3.2 MB/layer, fits per-XCD 4 MiB L2).
// easrc/easrc2 hold per-node (exp(a), exp(0.2a)) pairs for exp-factorized
// edge weights.
// ---------------------------------------------------------------------------
static constexpr size_t WS_FLAGS  = 0;        // 4 ints
static constexpr size_t WS_EASRC  = 4;        // 200000 (float2[N])
static constexpr size_t WS_ADST   = 200004;   // 100000
static constexpr size_t WS_EASRC2 = 300004;   // 200000 (float2[N])
static constexpr size_t WS_ADST2  = 500004;   // 100000
static constexpr size_t WS_BCNT   = 600004;   // 1024 ints
static constexpr size_t WS_ROWBEG = 601028;   // 100000 ints
static constexpr size_t WS_ROWCNT = 701028;   // 100000 ints
static constexpr size_t WS_HBUF   = 801028;   // 800000 fl = 1.6M bf16 (h1)
static constexpr size_t WS_H2BUF  = 1601028;  // 800000 fl = 1.6M bf16 (h2)
static constexpr size_t WS_BEDGES = 2401028;  // NBUCK*CAP_B = 4,003,840 ints
static constexpr size_t WS_SRCS   = 6404868;  // 4,003,840 ints
static constexpr size_t WS_BUCKET_END = WS_SRCS + (size_t)NBUCK * CAP_B; // 10,408,708
// fallback (fp32) regions: hbuf @WS_HBUF(1.6M fl), acc @WS_BEDGES(1.6M fl),
// denom @ 4,001,028
static constexpr size_t WS_FB_DEN     = 4001028;
static constexpr size_t WS_ATOMIC_END = 4101028;

__device__ __forceinline__ float lrelu(float v) { return v >= 0.f ? v : 0.2f * v; }
__device__ __forceinline__ float loadf(const void* p, int i, bool f32) {
    return f32 ? ((const float*)p)[i] : __bfloat162float(((const bf16*)p)[i]);
}
__device__ __forceinline__ unsigned short f2bf(float f) {   // RNE fp32->bf16 bits
    unsigned u = __float_as_uint(f);
    return (unsigned short)((u + 0x7FFFu + ((u >> 16) & 1u)) >> 16);
}
__device__ __forceinline__ float bf2f(unsigned short b) {
    return __uint_as_float((unsigned)b << 16);
}

// ---------------------------------------------------------------------------
// Probe (+ zero bcnt): bit0 = floats fp32 ; bit1 = edge_index int64
// ---------------------------------------------------------------------------
__global__ __launch_bounds__(256) void k_probe0(
    const void* __restrict__ x, const void* __restrict__ ei,
    int* __restrict__ flags, int* __restrict__ bcnt)
{
    __shared__ int cnt, nz;
    const int t = threadIdx.x;
    if (t == 0) { cnt = 0; nz = 0; }
    __syncthreads();
    const unsigned u = ((const unsigned*)x)[t];
    if ((u & 0x7FFFu) >= 0x4800u) atomicAdd(&cnt, 1);
    if (t < 64) {
        if (((const unsigned*)ei)[2 * t + 1] != 0u) atomicAdd(&nz, 1);
    }
    for (int i = t; i < 1024; i += 256) bcnt[i] = 0;
    __syncthreads();
    if (t == 0) flags[0] = ((cnt >= 16) ? 1 : 0) | ((nz == 0) ? 2 : 0);
}

// ---------------------------------------------------------------------------
// k_binfeat (1024 thr): [0,GRDB) bin w/ LDS edge cache (edge_index read once);
// [GRDB,+GRDN_F) feat1: h1=x@W1 (fp32 regs) -> bf16 store; easrc=(e^a, e^.2a).
// ---------------------------------------------------------------------------
__global__ __launch_bounds__(1024, 8) void k_binfeat(
    const void* __restrict__ ei, const void* __restrict__ x,
    const void* __restrict__ W1, const void* __restrict__ a_s,
    const void* __restrict__ a_d, const int* __restrict__ flags,
    int* __restrict__ bcnt, int* __restrict__ bedges,
    unsigned short* __restrict__ hbuf, float2* __restrict__ easrc,
    float* __restrict__ adst)
{
    __shared__ int            hist[NBUCK];
    __shared__ int            base[NBUCK];
    __shared__ int            cval[BIN_CHUNK];
    __shared__ unsigned short cbkt[BIN_CHUNK];
    __shared__ float Wl[F_IN * F_HID];
    __shared__ float asl[F_HID];
    __shared__ float adl[F_HID];
    const int t = threadIdx.x;
    const bool f32 = flags[0] & 1;
    const bool i64 = flags[0] & 2;

    if (blockIdx.x < GRDB) {
        const int e0 = blockIdx.x * BIN_CHUNK;
        const int valid = min(BIN_CHUNK, N_EDGES - e0);
        for (int i = t; i < NBUCK; i += 1024) hist[i] = 0;
        __syncthreads();
#pragma unroll
        for (int i = 0; i < BIN_CHUNK / 1024; ++i) {
            const int idx = i * 1024 + t;
            const int e = e0 + idx;
            if (idx < valid) {
                int s, d;
                if (i64) {
                    s = ((const int*)ei)[2 * (size_t)e];
                    d = ((const int*)ei)[2 * ((size_t)N_EDGES + e)];
                } else {
                    s = ((const int*)ei)[e];
                    d = ((const int*)ei)[(size_t)N_EDGES + e];
                }
                const int b = d >> BSHIFT;
                cval[idx] = (s << BSHIFT) | (d & (BNODES - 1));
                cbkt[idx] = (unsigned short)b;
                atomicAdd(&hist[b], 1);
            }
        }
        __syncthreads();
        for (int i = t; i < NBUCK; i += 1024) {
            const int c = hist[i];
            base[i] = c ? atomicAdd(&bcnt[i], c) : 0;
            hist[i] = 0;
        }
        __syncthreads();
#pragma unroll
        for (int i = 0; i < BIN_CHUNK / 1024; ++i) {
            const int idx = i * 1024 + t;
            if (idx < valid) {
                const int b = cbkt[idx];
                const int r = atomicAdd(&hist[b], 1);
                const int pos = base[b] + r;
                if (pos < CAP_B) bedges[(size_t)b * CAP_B + pos] = cval[idx];
            }
        }
    } else {
        for (int i = t; i < F_IN * F_HID; i += 1024) Wl[i] = loadf(W1, i, f32);
        if (t < F_HID) { asl[t] = loadf(a_s, t, f32); adl[t] = loadf(a_d, t, f32); }
        __syncthreads();
        const int node = (blockIdx.x - GRDB) * 1024 + t;
        if (node >= N_NODES) return;

        float h[F_HID];
#pragma unroll
        for (int k = 0; k < F_HID; ++k) h[k] = 0.f;
        if (f32) {
            const float2* xp = (const float2*)((const float*)x + (size_t)node * F_IN);
#pragma unroll
            for (int j = 0; j < F_IN / 2; ++j) {
                const float2 v = xp[j];
#pragma unroll
                for (int k = 0; k < F_HID; ++k) {
                    h[k] = fmaf(v.x, Wl[(2*j)   * F_HID + k], h[k]);
                    h[k] = fmaf(v.y, Wl[(2*j+1) * F_HID + k], h[k]);
                }
            }
        } else {
            const unsigned* xu = (const unsigned*)x + (size_t)node * (F_IN / 2);
#pragma unroll
            for (int j = 0; j < F_IN / 2; ++j) {
                const unsigned u = xu[j];
                const float v0 = __uint_as_float(u << 16);
                const float v1 = __uint_as_float(u & 0xFFFF0000u);
#pragma unroll
                for (int k = 0; k < F_HID; ++k) {
                    h[k] = fmaf(v0, Wl[(2*j)   * F_HID + k], h[k]);
                    h[k] = fmaf(v1, Wl[(2*j+1) * F_HID + k], h[k]);
                }
            }
        }
        float s = 0.f, d = 0.f;
#pragma unroll
        for (int k = 0; k < F_HID; ++k) { s = fmaf(h[k], asl[k], s); d = fmaf(h[k], adl[k], d); }
        easrc[node] = make_float2(__expf(s), __expf(0.2f * s));
        adst[node] = d;
        // pack 16 fp32 -> 16 bf16 (32 B) -> two uint4 stores
        unsigned pk[8];
#pragma unroll
        for (int q = 0; q < 8; ++q)
            pk[q] = (unsigned)f2bf(h[2*q]) | ((unsigned)f2bf(h[2*q+1]) << 16);
        uint4* hb = (uint4*)(hbuf + (size_t)node * F_HID);
        hb[0] = make_uint4(pk[0], pk[1], pk[2], pk[3]);
        hb[1] = make_uint4(pk[4], pk[5], pk[6], pk[7]);
    }
}

// ---------------------------------------------------------------------------
// k_bsort (512 thr): per-bucket LDS counting sort into 16B-padded segments.
// ---------------------------------------------------------------------------
__global__ __launch_bounds__(512) void k_bsort(
    const int* __restrict__ bcnt, const int* __restrict__ bedges,
    int* __restrict__ rowbeg, int* __restrict__ rowcnt, int* __restrict__ srcs)
{
    __shared__ int hist[BNODES];
    __shared__ int scan[BNODES];
    __shared__ int cur[BNODES];
    const int t = threadIdx.x;
    const int b = blockIdx.x;
    const int n0 = b << BSHIFT;
    if (t < BNODES) hist[t] = 0;
    __syncthreads();
    const int cnt = min(bcnt[b], CAP_B);
    const int* be = bedges + (size_t)b * CAP_B;
    for (int e = t; e < cnt; e += 512)
        atomicAdd(&hist[be[e] & (BNODES - 1)], 1);
    __syncthreads();
    if (t < BNODES) scan[t] = (hist[t] + 3) & ~3;
    __syncthreads();
#pragma unroll
    for (int off = 1; off < BNODES; off <<= 1) {
        const int v = (t < BNODES && t >= off) ? scan[t - off] : 0;
        __syncthreads();
        if (t < BNODES) scan[t] += v;
        __syncthreads();
    }
    if (t < BNODES) {
        const int ex = scan[t] - ((hist[t] + 3) & ~3);
        cur[t] = ex;
        const int node = n0 + t;
        if (node < N_NODES) {
            rowbeg[node] = b * CAP_B + ex;
            rowcnt[node] = hist[t];
        }
    }
    __syncthreads();
    for (int e = t; e < cnt; e += 512) {
        const int p = be[e];
        const int dl = p & (BNODES - 1);
        const int r = atomicAdd(&cur[dl], 1);
        if (r < CAP_B) srcs[(size_t)b * CAP_B + r] = p >> BSHIFT;
    }
}

// ---------------------------------------------------------------------------
// k_agg1: 16 lanes/node; per edge 8B easrc gather + 2B bf16 h gather;
// exp-factorized weight w = (E>=T ? E*Ead : F*F5ad). Epilogue fuses mid
// (z@W2 via width-16 shuffles) and writes bf16 h2 + easrc2/adst2.
// ---------------------------------------------------------------------------
__global__ __launch_bounds__(256) void k_agg1(
    const int* __restrict__ rowbeg, const int* __restrict__ rowcnt,
    const int* __restrict__ srcs,
    const float2* __restrict__ easrc, const float* __restrict__ adst,
    const unsigned short* __restrict__ h, const void* __restrict__ b1,
    const void* __restrict__ W2, const void* __restrict__ a_s2,
    const void* __restrict__ a_d2, const int* __restrict__ flags,
    unsigned short* __restrict__ h2buf, float2* __restrict__ easrc2,
    float* __restrict__ adst2)
{
    __shared__ float Wl[F_HID * F_HID];
    __shared__ float asl[F_HID];
    __shared__ float adl[F_HID];
    __shared__ float bl[F_HID];
    const bool f32 = flags[0] & 1;
    const int t = threadIdx.x;
    if (t < F_HID * F_HID) Wl[t] = loadf(W2, t, f32);
    if (t < F_HID) {
        asl[t] = loadf(a_s2, t, f32);
        adl[t] = loadf(a_d2, t, f32);
        bl[t]  = loadf(b1, t, f32);
    }
    __syncthreads();

    const int k = t & 15;
    const int node = blockIdx.x * 16 + (t >> 4);   // 6250*16 = 100000 exact
    const float adn  = adst[node];
    const float Ead  = __expf(adn);
    const float F5ad = __expf(0.2f * adn);
    const float T    = __expf(-adn);
    const float2 es  = easrc[node];
    const float w0 = (es.x >= T) ? es.x * Ead : es.y * F5ad;   // self-loop
    float denom = w0;
    float acc = w0 * bf2f(h[(size_t)node * F_HID + k]);
    const int n = rowcnt[node];
    const int* sp = srcs + rowbeg[node];
    int i = 0;
    for (; i + 8 <= n; i += 8) {
        const int4 sa = *(const int4*)(sp + i);
        const int4 sb = *(const int4*)(sp + i + 4);
        const float2 ea0 = easrc[sa.x], ea1 = easrc[sa.y];
        const float2 ea2 = easrc[sa.z], ea3 = easrc[sa.w];
        const float2 ea4 = easrc[sb.x], ea5 = easrc[sb.y];
        const float2 ea6 = easrc[sb.z], ea7 = easrc[sb.w];
        const float h0 = bf2f(h[(size_t)sa.x * F_HID + k]);
        const float h1 = bf2f(h[(size_t)sa.y * F_HID + k]);
        const float h2 = bf2f(h[(size_t)sa.z * F_HID + k]);
        const float h3 = bf2f(h[(size_t)sa.w * F_HID + k]);
        const float h4 = bf2f(h[(size_t)sb.x * F_HID + k]);
        const float h5 = bf2f(h[(size_t)sb.y * F_HID + k]);
        const float h6 = bf2f(h[(size_t)sb.z * F_HID + k]);
        const float h7 = bf2f(h[(size_t)sb.w * F_HID + k]);
        const float e0 = (ea0.x >= T) ? ea0.x * Ead : ea0.y * F5ad;
        const float e1 = (ea1.x >= T) ? ea1.x * Ead : ea1.y * F5ad;
        const float e2 = (ea2.x >= T) ? ea2.x * Ead : ea2.y * F5ad;
        const float e3 = (ea3.x >= T) ? ea3.x * Ead : ea3.y * F5ad;
        const float e4 = (ea4.x >= T) ? ea4.x * Ead : ea4.y * F5ad;
        const float e5 = (ea5.x >= T) ? ea5.x * Ead : ea5.y * F5ad;
        const float e6 = (ea6.x >= T) ? ea6.x * Ead : ea6.y * F5ad;
        const float e7 = (ea7.x >= T) ? ea7.x * Ead : ea7.y * F5ad;
        denom += (e0 + e1 + e2 + e3) + (e4 + e5 + e6 + e7);
        acc = fmaf(e0, h0, acc); acc = fmaf(e1, h1, acc);
        acc = fmaf(e2, h2, acc); acc = fmaf(e3, h3, acc);
        acc = fmaf(e4, h4, acc); acc = fmaf(e5, h5, acc);
        acc = fmaf(e6, h6, acc); acc = fmaf(e7, h7, acc);
    }
    for (; i < n; ++i) {
        const int s = sp[i];
        const float2 ea = easrc[s];
        const float w = (ea.x >= T) ? ea.x * Ead : ea.y * F5ad;
        denom += w;
        acc = fmaf(w, bf2f(h[(size_t)s * F_HID + k]), acc);
    }
    float z = acc / denom + bl[k];
    z = z > 0.f ? z : expm1f(z);

    float hh = 0.f;
#pragma unroll
    for (int j = 0; j < F_HID; ++j) {
        const float zj = __shfl(z, j, 16);
        hh = fmaf(zj, Wl[j * F_HID + k], hh);
    }
    float s2 = hh * asl[k], d2 = hh * adl[k];
#pragma unroll
    for (int off = 1; off < 16; off <<= 1) {
        s2 += __shfl_xor(s2, off, 16);
        d2 += __shfl_xor(d2, off, 16);
    }
    h2buf[(size_t)node * F_HID + k] = f2bf(hh);
    if (k == 0) {
        easrc2[node] = make_float2(__expf(s2), __expf(0.2f * s2));
        adst2[node] = d2;
    }
}

// ---------------------------------------------------------------------------
// k_agg2: gather-agg on layer-2 buffers; writes fp32 d_out.
// ---------------------------------------------------------------------------
__global__ __launch_bounds__(256) void k_agg2(
    const int* __restrict__ rowbeg, const int* __restrict__ rowcnt,
    const int* __restrict__ srcs,
    const float2* __restrict__ easrc, const float* __restrict__ adst,
    const unsigned short* __restrict__ h, const void* __restrict__ b2,
    const int* __restrict__ flags, float* __restrict__ outp)
{
    const bool f32 = flags[0] & 1;
    const int t = threadIdx.x;
    const int k = t & 15;
    const int node = blockIdx.x * 16 + (t >> 4);
    const float adn  = adst[node];
    const float Ead  = __expf(adn);
    const float F5ad = __expf(0.2f * adn);
    const float T    = __expf(-adn);
    const float2 es  = easrc[node];
    const float w0 = (es.x >= T) ? es.x * Ead : es.y * F5ad;
    float denom = w0;
    float acc = w0 * bf2f(h[(size_t)node * F_HID + k]);
    const int n = rowcnt[node];
    const int* sp = srcs + rowbeg[node];
    int i = 0;
    for (; i + 8 <= n; i += 8) {
        const int4 sa = *(const int4*)(sp + i);
        const int4 sb = *(const int4*)(sp + i + 4);
        const float2 ea0 = easrc[sa.x], ea1 = easrc[sa.y];
        const float2 ea2 = easrc[sa.z], ea3 = easrc[sa.w];
        const float2 ea4 = easrc[sb.x], ea5 = easrc[sb.y];
        const float2 ea6 = easrc[sb.z], ea7 = easrc[sb.w];
        const float h0 = bf2f(h[(size_t)sa.x * F_HID + k]);
        const float h1 = bf2f(h[(size_t)sa.y * F_HID + k]);
        const float h2 = bf2f(h[(size_t)sa.z * F_HID + k]);
        const float h3 = bf2f(h[(size_t)sa.w * F_HID + k]);
        const float h4 = bf2f(h[(size_t)sb.x * F_HID + k]);
        const float h5 = bf2f(h[(size_t)sb.y * F_HID + k]);
        const float h6 = bf2f(h[(size_t)sb.z * F_HID + k]);
        const float h7 = bf2f(h[(size_t)sb.w * F_HID + k]);
        const float e0 = (ea0.x >= T) ? ea0.x * Ead : ea0.y * F5ad;
        const float e1 = (ea1.x >= T) ? ea1.x * Ead : ea1.y * F5ad;
        const float e2 = (ea2.x >= T) ? ea2.x * Ead : ea2.y * F5ad;
        const float e3 = (ea3.x >= T) ? ea3.x * Ead : ea3.y * F5ad;
        const float e4 = (ea4.x >= T) ? ea4.x * Ead : ea4.y * F5ad;
        const float e5 = (ea5.x >= T) ? ea5.x * Ead : ea5.y * F5ad;
        const float e6 = (ea6.x >= T) ? ea6.x * Ead : ea6.y * F5ad;
        const float e7 = (ea7.x >= T) ? ea7.x * Ead : ea7.y * F5ad;
        denom += (e0 + e1 + e2 + e3) + (e4 + e5 + e6 + e7);
        acc = fmaf(e0, h0, acc); acc = fmaf(e1, h1, acc);
        acc = fmaf(e2, h2, acc); acc = fmaf(e3, h3, acc);
        acc = fmaf(e4, h4, acc); acc = fmaf(e5, h5, acc);
        acc = fmaf(e6, h6, acc); acc = fmaf(e7, h7, acc);
    }
    for (; i < n; ++i) {
        const int s = sp[i];
        const float2 ea = easrc[s];
        const float w = (ea.x >= T) ? ea.x * Ead : ea.y * F5ad;
        denom += w;
        acc = fmaf(w, bf2f(h[(size_t)s * F_HID + k]), acc);
    }
    outp[(size_t)node * F_HID + k] = acc / denom + loadf(b2, k, f32);
}

// ---------------------------------------------------------------------------
// Fallback kernels (round-3 proven atomic path, fp32 buffers) + diag
// ---------------------------------------------------------------------------
__global__ __launch_bounds__(256) void k_feat1(
    const void* __restrict__ x, const void* __restrict__ W1,
    const void* __restrict__ a_s, const void* __restrict__ a_d,
    const int* __restrict__ flags,
    float* __restrict__ hbuf, float* __restrict__ asrc, float* __restrict__ adst)
{
    const bool f32 = flags[0] & 1;
    __shared__ float Wl[F_IN * F_HID];
    __shared__ float asl[F_HID];
    __shared__ float adl[F_HID];
    const int t = threadIdx.x;
    for (int i = t; i < F_IN * F_HID; i += 256) Wl[i] = loadf(W1, i, f32);
    if (t < F_HID) { asl[t] = loadf(a_s, t, f32); adl[t] = loadf(a_d, t, f32); }
    __syncthreads();
    const int node = blockIdx.x * 256 + t;
    if (node >= N_NODES) return;
    float h[F_HID];
#pragma unroll
    for (int k = 0; k < F_HID; ++k) h[k] = 0.f;
    if (f32) {
        const float2* xp = (const float2*)((const float*)x + (size_t)node * F_IN);
#pragma unroll
        for (int j = 0; j < F_IN / 2; ++j) {
            const float2 v = xp[j];
#pragma unroll
            for (int k = 0; k < F_HID; ++k) {
                h[k] = fmaf(v.x, Wl[(2*j)   * F_HID + k], h[k]);
                h[k] = fmaf(v.y, Wl[(2*j+1) * F_HID + k], h[k]);
            }
        }
    } else {
        const unsigned* xu = (const unsigned*)x + (size_t)node * (F_IN / 2);
#pragma unroll
        for (int j = 0; j < F_IN / 2; ++j) {
            const unsigned u = xu[j];
            const float v0 = __uint_as_float(u << 16);
            const float v1 = __uint_as_float(u & 0xFFFF0000u);
#pragma unroll
            for (int k = 0; k < F_HID; ++k) {
                h[k] = fmaf(v0, Wl[(2*j)   * F_HID + k], h[k]);
                h[k] = fmaf(v1, Wl[(2*j+1) * F_HID + k], h[k]);
            }
        }
    }
    float s = 0.f, d = 0.f;
#pragma unroll
    for (int k = 0; k < F_HID; ++k) { s = fmaf(h[k], asl[k], s); d = fmaf(h[k], adl[k], d); }
    asrc[node] = s; adst[node] = d;
    float4* hb = (float4*)(hbuf + (size_t)node * F_HID);
#pragma unroll
    for (int q = 0; q < 4; ++q)
        hb[q] = make_float4(h[4*q], h[4*q+1], h[4*q+2], h[4*q+3]);
}

__global__ __launch_bounds__(256) void k_selfinit(
    const float* __restrict__ asrc, const float* __restrict__ adst,
    const float* __restrict__ h, float* __restrict__ denom, float* __restrict__ acc)
{
    const int t = blockIdx.x * 256 + threadIdx.x;
    if (t >= N_NODES * F_HID) return;
    const int n = t >> 4;
    const float w0 = __expf(lrelu(asrc[n] + adst[n]));
    if ((t & 15) == 0) denom[n] = w0;
    acc[t] = w0 * h[t];
}

__global__ __launch_bounds__(256) void k_edge(
    const void* __restrict__ ei, const int* __restrict__ flags,
    const float* __restrict__ asrc, const float* __restrict__ adst,
    const float* __restrict__ hbuf,
    float* __restrict__ denom, float* __restrict__ acc)
{
    const int e = blockIdx.x * 256 + threadIdx.x;
    if (e >= N_EDGES) return;
    int s, d;
    if (flags[0] & 2) {
        const long long* e64 = (const long long*)ei;
        s = (int)e64[e]; d = (int)e64[(size_t)N_EDGES + e];
    } else {
        const int* e32 = (const int*)ei;
        s = e32[e]; d = e32[(size_t)N_EDGES + e];
    }
    const float w = __expf(lrelu(asrc[s] + adst[d]));
    atomicAdd(&denom[d], w);
    const float4* hs = (const float4*)(hbuf + (size_t)s * F_HID);
    float* ad = acc + (size_t)d * F_HID;
#pragma unroll
    for (int q = 0; q < 4; ++q) {
        const float4 hv = hs[q];
        atomicAdd(ad + 4*q + 0, w * hv.x);
        atomicAdd(ad + 4*q + 1, w * hv.y);
        atomicAdd(ad + 4*q + 2, w * hv.z);
        atomicAdd(ad + 4*q + 3, w * hv.w);
    }
}

__global__ __launch_bounds__(256) void k_div_elu(
    float* __restrict__ acc, const float* __restrict__ denom,
    const void* __restrict__ b1, const int* __restrict__ flags)
{
    const bool f32 = flags[0] & 1;
    const int t = blockIdx.x * 256 + threadIdx.x;
    if (t >= N_NODES * F_HID) return;
    const float v = acc[t] / denom[t >> 4] + loadf(b1, t & 15, f32);
    acc[t] = v > 0.f ? v : expm1f(v);
}

__global__ __launch_bounds__(256) void k_mid(
    const float* __restrict__ z,
    const void* __restrict__ W2, const void* __restrict__ a_s2,
    const void* __restrict__ a_d2, const int* __restrict__ flags,
    float* __restrict__ h2, float* __restrict__ asrc, float* __restrict__ adst)
{
    const bool f32 = flags[0] & 1;
    __shared__ float Wl[F_HID * F_HID];
    __shared__ float asl[F_HID];
    __shared__ float adl[F_HID];
    const int t = threadIdx.x;
    if (t < F_HID * F_HID) Wl[t] = loadf(W2, t, f32);
    if (t < F_HID) { asl[t] = loadf(a_s2, t, f32); adl[t] = loadf(a_d2, t, f32); }
    __syncthreads();
    const int node = blockIdx.x * 256 + t;
    if (node >= N_NODES) return;
    float zr[F_HID];
    const float4* zi = (const float4*)(z + (size_t)node * F_HID);
#pragma unroll
    for (int q = 0; q < 4; ++q) {
        const float4 zv = zi[q];
        zr[4*q+0]=zv.x; zr[4*q+1]=zv.y; zr[4*q+2]=zv.z; zr[4*q+3]=zv.w;
    }
    float h[F_HID];
#pragma unroll
    for (int k = 0; k < F_HID; ++k) h[k] = 0.f;
#pragma unroll
    for (int j = 0; j < F_HID; ++j) {
        const float zv = zr[j];
#pragma unroll
        for (int k = 0; k < F_HID; ++k) h[k] = fmaf(zv, Wl[j * F_HID + k], h[k]);
    }
    float s = 0.f, d = 0.f;
#pragma unroll
    for (int k = 0; k < F_HID; ++k) { s = fmaf(h[k], asl[k], s); d = fmaf(h[k], adl[k], d); }
    asrc[node] = s; adst[node] = d;
    float4* hb = (float4*)(h2 + (size_t)node * F_HID);
#pragma unroll
    for (int q = 0; q < 4; ++q)
        hb[q] = make_float4(h[4*q], h[4*q+1], h[4*q+2], h[4*q+3]);
}

__global__ __launch_bounds__(256) void k_out(
    const float* __restrict__ acc, const float* __restrict__ denom,
    const void* __restrict__ b2, const int* __restrict__ flags,
    float* __restrict__ out)
{
    const bool f32 = flags[0] & 1;
    const int t = blockIdx.x * 256 + threadIdx.x;
    if (t >= N_NODES * F_HID) return;
    out[t] = acc[t] / denom[t >> 4] + loadf(b2, t & 15, f32);
}

__global__ __launch_bounds__(256) void k_diag(float* __restrict__ out, float v)
{
    const int t = blockIdx.x * 256 + threadIdx.x;
    if (t < N_NODES * F_HID) out[t] = v;
}

extern "C" void kernel_launch(void* const* d_in, const int* in_sizes, int n_in,
                              void* d_out, int out_size, void* d_ws, size_t ws_size,
                              hipStream_t stream) {
    const void* x   = d_in[0];
    const void* ei  = d_in[1];
    const void* W1  = d_in[2];
    const void* a1s = d_in[3];
    const void* a1d = d_in[4];
    const void* b1  = d_in[5];
    const void* W2  = d_in[6];
    const void* a2s = d_in[7];
    const void* a2d = d_in[8];
    const void* b2  = d_in[9];
    float* out = (float*)d_out;

    float* ws = (float*)d_ws;
    int*    flags  = (int*)(ws + WS_FLAGS);
    float2* easrc  = (float2*)(ws + WS_EASRC);
    float*  adst   = ws + WS_ADST;
    float2* easrc2 = (float2*)(ws + WS_EASRC2);
    float*  adst2  = ws + WS_ADST2;
    int*    bcnt   = (int*)(ws + WS_BCNT);
    int*    rowbeg = (int*)(ws + WS_ROWBEG);
    int*    rowcnt = (int*)(ws + WS_ROWCNT);
    unsigned short* hbuf  = (unsigned short*)(ws + WS_HBUF);
    unsigned short* h2buf = (unsigned short*)(ws + WS_H2BUF);
    int*    bedges = (int*)(ws + WS_BEDGES);
    int*    srcs   = (int*)(ws + WS_SRCS);

    const dim3 blk(256);
    const dim3 grdN((N_NODES + 255) / 256);
    const dim3 grdE((N_EDGES + 255) / 256);
    const dim3 grdO((N_NODES * F_HID + 255) / 256);
    const dim3 grdBF(GRDB + GRDN_F);
    const dim3 grdS(NBUCK);
    const dim3 grdA(N_NODES / 16);

    if (ws_size >= WS_BUCKET_END * 4) {
        k_probe0 <<<dim3(1), blk, 0, stream>>>(x, ei, flags, bcnt);
        k_binfeat<<<grdBF, dim3(1024), 0, stream>>>(ei, x, W1, a1s, a1d, flags,
                                                    bcnt, bedges, hbuf, easrc, adst);
        k_bsort  <<<grdS, dim3(512), 0, stream>>>(bcnt, bedges, rowbeg, rowcnt, srcs);
        k_agg1   <<<grdA, blk, 0, stream>>>(rowbeg, rowcnt, srcs, easrc, adst, hbuf,
                                            b1, W2, a2s, a2d, flags,
                                            h2buf, easrc2, adst2);
        k_agg2   <<<grdA, blk, 0, stream>>>(rowbeg, rowcnt, srcs, easrc2, adst2,
                                            h2buf, b2, flags, out);
    } else if (ws_size >= WS_ATOMIC_END * 4) {
        float* fb_h   = ws + WS_HBUF;      // 1.6M fp32
        float* fb_acc = ws + WS_BEDGES;    // 1.6M fp32
        float* fb_den = ws + WS_FB_DEN;    // 100k fp32
        float* fb_as  = ws + WS_EASRC;     // raw alpha_src
        float* fb_ad  = ws + WS_ADST;
        k_probe0 <<<dim3(1), blk, 0, stream>>>(x, ei, flags, bcnt);
        k_feat1  <<<grdN, blk, 0, stream>>>(x, W1, a1s, a1d, flags, fb_h, fb_as, fb_ad);
        k_selfinit<<<grdO, blk, 0, stream>>>(fb_as, fb_ad, fb_h, fb_den, fb_acc);
        k_edge   <<<grdE, blk, 0, stream>>>(ei, flags, fb_as, fb_ad, fb_h, fb_den, fb_acc);
        k_div_elu<<<grdO, blk, 0, stream>>>(fb_acc, fb_den, b1, flags);
        k_mid    <<<grdN, blk, 0, stream>>>(fb_acc, W2, a2s, a2d, flags, fb_h, fb_as, fb_ad);
        k_selfinit<<<grdO, blk, 0, stream>>>(fb_as, fb_ad, fb_h, fb_den, fb_acc);
        k_edge   <<<grdE, blk, 0, stream>>>(ei, flags, fb_as, fb_ad, fb_h, fb_den, fb_acc);
        k_out    <<<grdO, blk, 0, stream>>>(fb_acc, fb_den, b2, flags, out);
    } else {
        k_diag<<<grdO, blk, 0, stream>>>(out, (float)(ws_size >> 10));
    }
}

// Round 11
// 266.103 us; speedup vs baseline: 1.1147x; 1.1147x over previous
//
#include <hip/hip_runtime.h>
#include <hip/hip_bf16.h>

typedef __hip_bfloat16 bf16;

static constexpr int N_NODES = 100000;
static constexpr int N_EDGES = 3200000;
static constexpr int F_IN    = 54;
static constexpr int F_HID   = 16;

// bucket/CSR path
static constexpr int BSHIFT    = 7;                  // 128 nodes per bucket
static constexpr int BNODES    = 128;
static constexpr int NBUCK     = (N_NODES + BNODES - 1) / BNODES;  // 782
static constexpr int CAP_B     = 5120;
static constexpr int BIN_CHUNK = 8192;
static constexpr int GRDB      = (N_EDGES + BIN_CHUNK - 1) / BIN_CHUNK;  // 391
static constexpr int GRDN_F    = (N_NODES + 1023) / 1024;                // 98

// ---------------------------------------------------------------------------
// ws layout (float indices). End = 11,608,708 fl = 46.4 MB (< proven 52.4 MB).
// hc1/hc2: combined per-node 64-B rows, dword k = bf16(h[k]) | bf16(a_src)<<16
// -> ONE gather request per edge (lane k loads dword k of src row).
// ---------------------------------------------------------------------------
static constexpr size_t WS_FLAGS  = 0;        // 4 ints
static constexpr size_t WS_ADST   = 4;        // 100000
static constexpr size_t WS_ADST2  = 100004;   // 100000
static constexpr size_t WS_BCNT   = 200004;   // 1024 ints
static constexpr size_t WS_ROWBEG = 201028;   // 100000 ints
static constexpr size_t WS_ROWCNT = 301028;   // 100000 ints
static constexpr size_t WS_HC1    = 401028;   // 1,600,000 dw (combined rows L1)
static constexpr size_t WS_HC2    = 2001028;  // 1,600,000 dw (combined rows L2)
static constexpr size_t WS_BEDGES = 3601028;  // NBUCK*CAP_B = 4,003,840 ints
static constexpr size_t WS_SRCS   = 7604868;  // 4,003,840 ints
static constexpr size_t WS_BUCKET_END = WS_SRCS + (size_t)NBUCK * CAP_B; // 11,608,708
// fallback fp32 regions: h @WS_HC1, acc @WS_HC2, denom/asrc @WS_BEDGES..
static constexpr size_t WS_FB_DEN     = 3601028;
static constexpr size_t WS_FB_AS      = 3701028;
static constexpr size_t WS_ATOMIC_END = 3801028;

__device__ __forceinline__ float lrelu(float v) { return v >= 0.f ? v : 0.2f * v; }
__device__ __forceinline__ float loadf(const void* p, int i, bool f32) {
    return f32 ? ((const float*)p)[i] : __bfloat162float(((const bf16*)p)[i]);
}
__device__ __forceinline__ unsigned f2bf(float f) {   // RNE fp32->bf16 bits
    unsigned u = __float_as_uint(f);
    return (u + 0x7FFFu + ((u >> 16) & 1u)) >> 16;
}

// ---------------------------------------------------------------------------
// Probe (+ zero bcnt): bit0 = floats fp32 ; bit1 = edge_index int64
// ---------------------------------------------------------------------------
__global__ __launch_bounds__(256) void k_probe0(
    const void* __restrict__ x, const void* __restrict__ ei,
    int* __restrict__ flags, int* __restrict__ bcnt)
{
    __shared__ int cnt, nz;
    const int t = threadIdx.x;
    if (t == 0) { cnt = 0; nz = 0; }
    __syncthreads();
    const unsigned u = ((const unsigned*)x)[t];
    if ((u & 0x7FFFu) >= 0x4800u) atomicAdd(&cnt, 1);
    if (t < 64) {
        if (((const unsigned*)ei)[2 * t + 1] != 0u) atomicAdd(&nz, 1);
    }
    for (int i = t; i < 1024; i += 256) bcnt[i] = 0;
    __syncthreads();
    if (t == 0) flags[0] = ((cnt >= 16) ? 1 : 0) | ((nz == 0) ? 2 : 0);
}

// ---------------------------------------------------------------------------
// k_binfeat (1024 thr): [0,GRDB) bin w/ LDS edge cache; [GRDB,+GRDN_F) feat1:
// h1 = x@W1 (fp32 regs); emits combined row dword k = bf16(h[k])|bf16(a)<<16.
// ---------------------------------------------------------------------------
__global__ __launch_bounds__(1024, 8) void k_binfeat(
    const void* __restrict__ ei, const void* __restrict__ x,
    const void* __restrict__ W1, const void* __restrict__ a_s,
    const void* __restrict__ a_d, const int* __restrict__ flags,
    int* __restrict__ bcnt, int* __restrict__ bedges,
    unsigned* __restrict__ hc, float* __restrict__ adst)
{
    __shared__ int            hist[NBUCK];
    __shared__ int            base[NBUCK];
    __shared__ int            cval[BIN_CHUNK];
    __shared__ unsigned short cbkt[BIN_CHUNK];
    __shared__ float Wl[F_IN * F_HID];
    __shared__ float asl[F_HID];
    __shared__ float adl[F_HID];
    const int t = threadIdx.x;
    const bool f32 = flags[0] & 1;
    const bool i64 = flags[0] & 2;

    if (blockIdx.x < GRDB) {
        const int e0 = blockIdx.x * BIN_CHUNK;
        const int valid = min(BIN_CHUNK, N_EDGES - e0);
        for (int i = t; i < NBUCK; i += 1024) hist[i] = 0;
        __syncthreads();
#pragma unroll
        for (int i = 0; i < BIN_CHUNK / 1024; ++i) {
            const int idx = i * 1024 + t;
            const int e = e0 + idx;
            if (idx < valid) {
                int s, d;
                if (i64) {
                    s = ((const int*)ei)[2 * (size_t)e];
                    d = ((const int*)ei)[2 * ((size_t)N_EDGES + e)];
                } else {
                    s = ((const int*)ei)[e];
                    d = ((const int*)ei)[(size_t)N_EDGES + e];
                }
                const int b = d >> BSHIFT;
                cval[idx] = (s << BSHIFT) | (d & (BNODES - 1));
                cbkt[idx] = (unsigned short)b;
                atomicAdd(&hist[b], 1);
            }
        }
        __syncthreads();
        for (int i = t; i < NBUCK; i += 1024) {
            const int c = hist[i];
            base[i] = c ? atomicAdd(&bcnt[i], c) : 0;
            hist[i] = 0;
        }
        __syncthreads();
#pragma unroll
        for (int i = 0; i < BIN_CHUNK / 1024; ++i) {
            const int idx = i * 1024 + t;
            if (idx < valid) {
                const int b = cbkt[idx];
                const int r = atomicAdd(&hist[b], 1);
                const int pos = base[b] + r;
                if (pos < CAP_B) bedges[(size_t)b * CAP_B + pos] = cval[idx];
            }
        }
    } else {
        for (int i = t; i < F_IN * F_HID; i += 1024) Wl[i] = loadf(W1, i, f32);
        if (t < F_HID) { asl[t] = loadf(a_s, t, f32); adl[t] = loadf(a_d, t, f32); }
        __syncthreads();
        const int node = (blockIdx.x - GRDB) * 1024 + t;
        if (node >= N_NODES) return;

        float h[F_HID];
#pragma unroll
        for (int k = 0; k < F_HID; ++k) h[k] = 0.f;
        if (f32) {
            const float2* xp = (const float2*)((const float*)x + (size_t)node * F_IN);
#pragma unroll
            for (int j = 0; j < F_IN / 2; ++j) {
                const float2 v = xp[j];
#pragma unroll
                for (int k = 0; k < F_HID; ++k) {
                    h[k] = fmaf(v.x, Wl[(2*j)   * F_HID + k], h[k]);
                    h[k] = fmaf(v.y, Wl[(2*j+1) * F_HID + k], h[k]);
                }
            }
        } else {
            const unsigned* xu = (const unsigned*)x + (size_t)node * (F_IN / 2);
#pragma unroll
            for (int j = 0; j < F_IN / 2; ++j) {
                const unsigned u = xu[j];
                const float v0 = __uint_as_float(u << 16);
                const float v1 = __uint_as_float(u & 0xFFFF0000u);
#pragma unroll
                for (int k = 0; k < F_HID; ++k) {
                    h[k] = fmaf(v0, Wl[(2*j)   * F_HID + k], h[k]);
                    h[k] = fmaf(v1, Wl[(2*j+1) * F_HID + k], h[k]);
                }
            }
        }
        float s = 0.f, d = 0.f;
#pragma unroll
        for (int k = 0; k < F_HID; ++k) { s = fmaf(h[k], asl[k], s); d = fmaf(h[k], adl[k], d); }
        adst[node] = d;
        const unsigned ab = f2bf(s) << 16;
        unsigned pk[F_HID];
#pragma unroll
        for (int k = 0; k < F_HID; ++k) pk[k] = f2bf(h[k]) | ab;
        uint4* hb = (uint4*)(hc + (size_t)node * F_HID);
#pragma unroll
        for (int q = 0; q < 4; ++q)
            hb[q] = make_uint4(pk[4*q], pk[4*q+1], pk[4*q+2], pk[4*q+3]);
    }
}

// ---------------------------------------------------------------------------
// k_bsort (512 thr): per-bucket LDS counting sort into 16B-padded segments.
// ---------------------------------------------------------------------------
__global__ __launch_bounds__(512) void k_bsort(
    const int* __restrict__ bcnt, const int* __restrict__ bedges,
    int* __restrict__ rowbeg, int* __restrict__ rowcnt, int* __restrict__ srcs)
{
    __shared__ int hist[BNODES];
    __shared__ int scan[BNODES];
    __shared__ int cur[BNODES];
    const int t = threadIdx.x;
    const int b = blockIdx.x;
    const int n0 = b << BSHIFT;
    if (t < BNODES) hist[t] = 0;
    __syncthreads();
    const int cnt = min(bcnt[b], CAP_B);
    const int* be = bedges + (size_t)b * CAP_B;
    for (int e = t; e < cnt; e += 512)
        atomicAdd(&hist[be[e] & (BNODES - 1)], 1);
    __syncthreads();
    if (t < BNODES) scan[t] = (hist[t] + 3) & ~3;
    __syncthreads();
#pragma unroll
    for (int off = 1; off < BNODES; off <<= 1) {
        const int v = (t < BNODES && t >= off) ? scan[t - off] : 0;
        __syncthreads();
        if (t < BNODES) scan[t] += v;
        __syncthreads();
    }
    if (t < BNODES) {
        const int ex = scan[t] - ((hist[t] + 3) & ~3);
        cur[t] = ex;
        const int node = n0 + t;
        if (node < N_NODES) {
            rowbeg[node] = b * CAP_B + ex;
            rowcnt[node] = hist[t];
        }
    }
    __syncthreads();
    for (int e = t; e < cnt; e += 512) {
        const int p = be[e];
        const int dl = p & (BNODES - 1);
        const int r = atomicAdd(&cur[dl], 1);
        if (r < CAP_B) srcs[(size_t)b * CAP_B + r] = p >> BSHIFT;
    }
}

// ---------------------------------------------------------------------------
// k_agg1: 16 lanes/node. Per edge ONE 64-B row gather: lane k's dword holds
// bf16 h[k] (low) + bf16 a_src (high). w = exp(lrelu(a+adn)). Epilogue fuses
// mid (z@W2 via width-16 shuffles) and emits the layer-2 combined row.
// ---------------------------------------------------------------------------
__global__ __launch_bounds__(256) void k_agg1(
    const int* __restrict__ rowbeg, const int* __restrict__ rowcnt,
    const int* __restrict__ srcs, const float* __restrict__ adst,
    const unsigned* __restrict__ hc, const void* __restrict__ b1,
    const void* __restrict__ W2, const void* __restrict__ a_s2,
    const void* __restrict__ a_d2, const int* __restrict__ flags,
    unsigned* __restrict__ hc2, float* __restrict__ adst2)
{
    __shared__ float Wl[F_HID * F_HID];
    __shared__ float asl[F_HID];
    __shared__ float adl[F_HID];
    __shared__ float bl[F_HID];
    const bool f32 = flags[0] & 1;
    const int t = threadIdx.x;
    if (t < F_HID * F_HID) Wl[t] = loadf(W2, t, f32);
    if (t < F_HID) {
        asl[t] = loadf(a_s2, t, f32);
        adl[t] = loadf(a_d2, t, f32);
        bl[t]  = loadf(b1, t, f32);
    }
    __syncthreads();

    const int k = t & 15;
    const int node = blockIdx.x * 16 + (t >> 4);   // 6250*16 = 100000 exact
    const float adn = adst[node];
    const unsigned vs = hc[(size_t)node * F_HID + k];
    const float w0 = __expf(lrelu(__uint_as_float(vs & 0xFFFF0000u) + adn));
    float denom = w0;
    float acc = w0 * __uint_as_float(vs << 16);
    const int n = rowcnt[node];
    const int* sp = srcs + rowbeg[node];
    int i = 0;
    for (; i + 8 <= n; i += 8) {
        const int4 sa = *(const int4*)(sp + i);
        const int4 sb = *(const int4*)(sp + i + 4);
        const unsigned v0 = hc[(size_t)sa.x * F_HID + k];
        const unsigned v1 = hc[(size_t)sa.y * F_HID + k];
        const unsigned v2 = hc[(size_t)sa.z * F_HID + k];
        const unsigned v3 = hc[(size_t)sa.w * F_HID + k];
        const unsigned v4 = hc[(size_t)sb.x * F_HID + k];
        const unsigned v5 = hc[(size_t)sb.y * F_HID + k];
        const unsigned v6 = hc[(size_t)sb.z * F_HID + k];
        const unsigned v7 = hc[(size_t)sb.w * F_HID + k];
        const float e0 = __expf(lrelu(__uint_as_float(v0 & 0xFFFF0000u) + adn));
        const float e1 = __expf(lrelu(__uint_as_float(v1 & 0xFFFF0000u) + adn));
        const float e2 = __expf(lrelu(__uint_as_float(v2 & 0xFFFF0000u) + adn));
        const float e3 = __expf(lrelu(__uint_as_float(v3 & 0xFFFF0000u) + adn));
        const float e4 = __expf(lrelu(__uint_as_float(v4 & 0xFFFF0000u) + adn));
        const float e5 = __expf(lrelu(__uint_as_float(v5 & 0xFFFF0000u) + adn));
        const float e6 = __expf(lrelu(__uint_as_float(v6 & 0xFFFF0000u) + adn));
        const float e7 = __expf(lrelu(__uint_as_float(v7 & 0xFFFF0000u) + adn));
        denom += (e0 + e1 + e2 + e3) + (e4 + e5 + e6 + e7);
        acc = fmaf(e0, __uint_as_float(v0 << 16), acc);
        acc = fmaf(e1, __uint_as_float(v1 << 16), acc);
        acc = fmaf(e2, __uint_as_float(v2 << 16), acc);
        acc = fmaf(e3, __uint_as_float(v3 << 16), acc);
        acc = fmaf(e4, __uint_as_float(v4 << 16), acc);
        acc = fmaf(e5, __uint_as_float(v5 << 16), acc);
        acc = fmaf(e6, __uint_as_float(v6 << 16), acc);
        acc = fmaf(e7, __uint_as_float(v7 << 16), acc);
    }
    for (; i < n; ++i) {
        const unsigned v = hc[(size_t)sp[i] * F_HID + k];
        const float w = __expf(lrelu(__uint_as_float(v & 0xFFFF0000u) + adn));
        denom += w;
        acc = fmaf(w, __uint_as_float(v << 16), acc);
    }
    float z = acc / denom + bl[k];
    z = z > 0.f ? z : expm1f(z);

    float hh = 0.f;
#pragma unroll
    for (int j = 0; j < F_HID; ++j) {
        const float zj = __shfl(z, j, 16);
        hh = fmaf(zj, Wl[j * F_HID + k], hh);
    }
    float s2 = hh * asl[k], d2 = hh * adl[k];
#pragma unroll
    for (int off = 1; off < 16; off <<= 1) {
        s2 += __shfl_xor(s2, off, 16);
        d2 += __shfl_xor(d2, off, 16);
    }
    hc2[(size_t)node * F_HID + k] = f2bf(hh) | (f2bf(s2) << 16);
    if (k == 0) adst2[node] = d2;
}

// ---------------------------------------------------------------------------
// k_agg2: same one-request-per-edge gather on layer-2 rows; writes fp32 out.
// ---------------------------------------------------------------------------
__global__ __launch_bounds__(256) void k_agg2(
    const int* __restrict__ rowbeg, const int* __restrict__ rowcnt,
    const int* __restrict__ srcs, const float* __restrict__ adst,
    const unsigned* __restrict__ hc, const void* __restrict__ b2,
    const int* __restrict__ flags, float* __restrict__ outp)
{
    const bool f32 = flags[0] & 1;
    const int t = threadIdx.x;
    const int k = t & 15;
    const int node = blockIdx.x * 16 + (t >> 4);
    const float adn = adst[node];
    const unsigned vs = hc[(size_t)node * F_HID + k];
    const float w0 = __expf(lrelu(__uint_as_float(vs & 0xFFFF0000u) + adn));
    float denom = w0;
    float acc = w0 * __uint_as_float(vs << 16);
    const int n = rowcnt[node];
    const int* sp = srcs + rowbeg[node];
    int i = 0;
    for (; i + 8 <= n; i += 8) {
        const int4 sa = *(const int4*)(sp + i);
        const int4 sb = *(const int4*)(sp + i + 4);
        const unsigned v0 = hc[(size_t)sa.x * F_HID + k];
        const unsigned v1 = hc[(size_t)sa.y * F_HID + k];
        const unsigned v2 = hc[(size_t)sa.z * F_HID + k];
        const unsigned v3 = hc[(size_t)sa.w * F_HID + k];
        const unsigned v4 = hc[(size_t)sb.x * F_HID + k];
        const unsigned v5 = hc[(size_t)sb.y * F_HID + k];
        const unsigned v6 = hc[(size_t)sb.z * F_HID + k];
        const unsigned v7 = hc[(size_t)sb.w * F_HID + k];
        const float e0 = __expf(lrelu(__uint_as_float(v0 & 0xFFFF0000u) + adn));
        const float e1 = __expf(lrelu(__uint_as_float(v1 & 0xFFFF0000u) + adn));
        const float e2 = __expf(lrelu(__uint_as_float(v2 & 0xFFFF0000u) + adn));
        const float e3 = __expf(lrelu(__uint_as_float(v3 & 0xFFFF0000u) + adn));
        const float e4 = __expf(lrelu(__uint_as_float(v4 & 0xFFFF0000u) + adn));
        const float e5 = __expf(lrelu(__uint_as_float(v5 & 0xFFFF0000u) + adn));
        const float e6 = __expf(lrelu(__uint_as_float(v6 & 0xFFFF0000u) + adn));
        const float e7 = __expf(lrelu(__uint_as_float(v7 & 0xFFFF0000u) + adn));
        denom += (e0 + e1 + e2 + e3) + (e4 + e5 + e6 + e7);
        acc = fmaf(e0, __uint_as_float(v0 << 16), acc);
        acc = fmaf(e1, __uint_as_float(v1 << 16), acc);
        acc = fmaf(e2, __uint_as_float(v2 << 16), acc);
        acc = fmaf(e3, __uint_as_float(v3 << 16), acc);
        acc = fmaf(e4, __uint_as_float(v4 << 16), acc);
        acc = fmaf(e5, __uint_as_float(v5 << 16), acc);
        acc = fmaf(e6, __uint_as_float(v6 << 16), acc);
        acc = fmaf(e7, __uint_as_float(v7 << 16), acc);
    }
    for (; i < n; ++i) {
        const unsigned v = hc[(size_t)sp[i] * F_HID + k];
        const float w = __expf(lrelu(__uint_as_float(v & 0xFFFF0000u) + adn));
        denom += w;
        acc = fmaf(w, __uint_as_float(v << 16), acc);
    }
    outp[(size_t)node * F_HID + k] = acc / denom + loadf(b2, k, f32);
}

// ---------------------------------------------------------------------------
// Fallback kernels (round-3 proven atomic path, fp32 buffers) + diag
// ---------------------------------------------------------------------------
__global__ __launch_bounds__(256) void k_feat1(
    const void* __restrict__ x, const void* __restrict__ W1,
    const void* __restrict__ a_s, const void* __restrict__ a_d,
    const int* __restrict__ flags,
    float* __restrict__ hbuf, float* __restrict__ asrc, float* __restrict__ adst)
{
    const bool f32 = flags[0] & 1;
    __shared__ float Wl[F_IN * F_HID];
    __shared__ float asl[F_HID];
    __shared__ float adl[F_HID];
    const int t = threadIdx.x;
    for (int i = t; i < F_IN * F_HID; i += 256) Wl[i] = loadf(W1, i, f32);
    if (t < F_HID) { asl[t] = loadf(a_s, t, f32); adl[t] = loadf(a_d, t, f32); }
    __syncthreads();
    const int node = blockIdx.x * 256 + t;
    if (node >= N_NODES) return;
    float h[F_HID];
#pragma unroll
    for (int k = 0; k < F_HID; ++k) h[k] = 0.f;
    if (f32) {
        const float2* xp = (const float2*)((const float*)x + (size_t)node * F_IN);
#pragma unroll
        for (int j = 0; j < F_IN / 2; ++j) {
            const float2 v = xp[j];
#pragma unroll
            for (int k = 0; k < F_HID; ++k) {
                h[k] = fmaf(v.x, Wl[(2*j)   * F_HID + k], h[k]);
                h[k] = fmaf(v.y, Wl[(2*j+1) * F_HID + k], h[k]);
            }
        }
    } else {
        const unsigned* xu = (const unsigned*)x + (size_t)node * (F_IN / 2);
#pragma unroll
        for (int j = 0; j < F_IN / 2; ++j) {
            const unsigned u = xu[j];
            const float v0 = __uint_as_float(u << 16);
            const float v1 = __uint_as_float(u & 0xFFFF0000u);
#pragma unroll
            for (int k = 0; k < F_HID; ++k) {
                h[k] = fmaf(v0, Wl[(2*j)   * F_HID + k], h[k]);
                h[k] = fmaf(v1, Wl[(2*j+1) * F_HID + k], h[k]);
            }
        }
    }
    float s = 0.f, d = 0.f;
#pragma unroll
    for (int k = 0; k < F_HID; ++k) { s = fmaf(h[k], asl[k], s); d = fmaf(h[k], adl[k], d); }
    asrc[node] = s; adst[node] = d;
    float4* hb = (float4*)(hbuf + (size_t)node * F_HID);
#pragma unroll
    for (int q = 0; q < 4; ++q)
        hb[q] = make_float4(h[4*q], h[4*q+1], h[4*q+2], h[4*q+3]);
}

__global__ __launch_bounds__(256) void k_selfinit(
    const float* __restrict__ asrc, const float* __restrict__ adst,
    const float* __restrict__ h, float* __restrict__ denom, float* __restrict__ acc)
{
    const int t = blockIdx.x * 256 + threadIdx.x;
    if (t >= N_NODES * F_HID) return;
    const int n = t >> 4;
    const float w0 = __expf(lrelu(asrc[n] + adst[n]));
    if ((t & 15) == 0) denom[n] = w0;
    acc[t] = w0 * h[t];
}

__global__ __launch_bounds__(256) void k_edge(
    const void* __restrict__ ei, const int* __restrict__ flags,
    const float* __restrict__ asrc, const float* __restrict__ adst,
    const float* __restrict__ hbuf,
    float* __restrict__ denom, float* __restrict__ acc)
{
    const int e = blockIdx.x * 256 + threadIdx.x;
    if (e >= N_EDGES) return;
    int s, d;
    if (flags[0] & 2) {
        const long long* e64 = (const long long*)ei;
        s = (int)e64[e]; d = (int)e64[(size_t)N_EDGES + e];
    } else {
        const int* e32 = (const int*)ei;
        s = e32[e]; d = e32[(size_t)N_EDGES + e];
    }
    const float w = __expf(lrelu(asrc[s] + adst[d]));
    atomicAdd(&denom[d], w);
    const float4* hs = (const float4*)(hbuf + (size_t)s * F_HID);
    float* ad = acc + (size_t)d * F_HID;
#pragma unroll
    for (int q = 0; q < 4; ++q) {
        const float4 hv = hs[q];
        atomicAdd(ad + 4*q + 0, w * hv.x);
        atomicAdd(ad + 4*q + 1, w * hv.y);
        atomicAdd(ad + 4*q + 2, w * hv.z);
        atomicAdd(ad + 4*q + 3, w * hv.w);
    }
}

__global__ __launch_bounds__(256) void k_div_elu(
    float* __restrict__ acc, const float* __restrict__ denom,
    const void* __restrict__ b1, const int* __restrict__ flags)
{
    const bool f32 = flags[0] & 1;
    const int t = blockIdx.x * 256 + threadIdx.x;
    if (t >= N_NODES * F_HID) return;
    const float v = acc[t] / denom[t >> 4] + loadf(b1, t & 15, f32);
    acc[t] = v > 0.f ? v : expm1f(v);
}

__global__ __launch_bounds__(256) void k_mid(
    const float* __restrict__ z,
    const void* __restrict__ W2, const void* __restrict__ a_s2,
    const void* __restrict__ a_d2, const int* __restrict__ flags,
    float* __restrict__ h2, float* __restrict__ asrc, float* __restrict__ adst)
{
    const bool f32 = flags[0] & 1;
    __shared__ float Wl[F_HID * F_HID];
    __shared__ float asl[F_HID];
    __shared__ float adl[F_HID];
    const int t = threadIdx.x;
    if (t < F_HID * F_HID) Wl[t] = loadf(W2, t, f32);
    if (t < F_HID) { asl[t] = loadf(a_s2, t, f32); adl[t] = loadf(a_d2, t, f32); }
    __syncthreads();
    const int node = blockIdx.x * 256 + t;
    if (node >= N_NODES) return;
    float zr[F_HID];
    const float4* zi = (const float4*)(z + (size_t)node * F_HID);
#pragma unroll
    for (int q = 0; q < 4; ++q) {
        const float4 zv = zi[q];
        zr[4*q+0]=zv.x; zr[4*q+1]=zv.y; zr[4*q+2]=zv.z; zr[4*q+3]=zv.w;
    }
    float h[F_HID];
#pragma unroll
    for (int k = 0; k < F_HID; ++k) h[k] = 0.f;
#pragma unroll
    for (int j = 0; j < F_HID; ++j) {
        const float zv = zr[j];
#pragma unroll
        for (int k = 0; k < F_HID; ++k) h[k] = fmaf(zv, Wl[j * F_HID + k], h[k]);
    }
    float s = 0.f, d = 0.f;
#pragma unroll
    for (int k = 0; k < F_HID; ++k) { s = fmaf(h[k], asl[k], s); d = fmaf(h[k], adl[k], d); }
    asrc[node] = s; adst[node] = d;
    float4* hb = (float4*)(h2 + (size_t)node * F_HID);
#pragma unroll
    for (int q = 0; q < 4; ++q)
        hb[q] = make_float4(h[4*q], h[4*q+1], h[4*q+2], h[4*q+3]);
}

__global__ __launch_bounds__(256) void k_out(
    const float* __restrict__ acc, const float* __restrict__ denom,
    const void* __restrict__ b2, const int* __restrict__ flags,
    float* __restrict__ out)
{
    const bool f32 = flags[0] & 1;
    const int t = blockIdx.x * 256 + threadIdx.x;
    if (t >= N_NODES * F_HID) return;
    out[t] = acc[t] / denom[t >> 4] + loadf(b2, t & 15, f32);
}

__global__ __launch_bounds__(256) void k_diag(float* __restrict__ out, float v)
{
    const int t = blockIdx.x * 256 + threadIdx.x;
    if (t < N_NODES * F_HID) out[t] = v;
}

extern "C" void kernel_launch(void* const* d_in, const int* in_sizes, int n_in,
                              void* d_out, int out_size, void* d_ws, size_t ws_size,
                              hipStream_t stream) {
    const void* x   = d_in[0];
    const void* ei  = d_in[1];
    const void* W1  = d_in[2];
    const void* a1s = d_in[3];
    const void* a1d = d_in[4];
    const void* b1  = d_in[5];
    const void* W2  = d_in[6];
    const void* a2s = d_in[7];
    const void* a2d = d_in[8];
    const void* b2  = d_in[9];
    float* out = (float*)d_out;

    float* ws = (float*)d_ws;
    int*      flags  = (int*)(ws + WS_FLAGS);
    float*    adst   = ws + WS_ADST;
    float*    adst2  = ws + WS_ADST2;
    int*      bcnt   = (int*)(ws + WS_BCNT);
    int*      rowbeg = (int*)(ws + WS_ROWBEG);
    int*      rowcnt = (int*)(ws + WS_ROWCNT);
    unsigned* hc1    = (unsigned*)(ws + WS_HC1);
    unsigned* hc2    = (unsigned*)(ws + WS_HC2);
    int*      bedges = (int*)(ws + WS_BEDGES);
    int*      srcs   = (int*)(ws + WS_SRCS);

    const dim3 blk(256);
    const dim3 grdN((N_NODES + 255) / 256);
    const dim3 grdE((N_EDGES + 255) / 256);
    const dim3 grdO((N_NODES * F_HID + 255) / 256);
    const dim3 grdBF(GRDB + GRDN_F);
    const dim3 grdS(NBUCK);
    const dim3 grdA(N_NODES / 16);

    if (ws_size >= WS_BUCKET_END * 4) {
        k_probe0 <<<dim3(1), blk, 0, stream>>>(x, ei, flags, bcnt);
        k_binfeat<<<grdBF, dim3(1024), 0, stream>>>(ei, x, W1, a1s, a1d, flags,
                                                    bcnt, bedges, hc1, adst);
        k_bsort  <<<grdS, dim3(512), 0, stream>>>(bcnt, bedges, rowbeg, rowcnt, srcs);
        k_agg1   <<<grdA, blk, 0, stream>>>(rowbeg, rowcnt, srcs, adst, hc1,
                                            b1, W2, a2s, a2d, flags, hc2, adst2);
        k_agg2   <<<grdA, blk, 0, stream>>>(rowbeg, rowcnt, srcs, adst2, hc2,
                                            b2, flags, out);
    } else if (ws_size >= WS_ATOMIC_END * 4) {
        float* fb_h   = ws + WS_HC1;     // 1.6M fp32
        float* fb_acc = ws + WS_HC2;     // 1.6M fp32
        float* fb_den = ws + WS_FB_DEN;  // 100k
        float* fb_as  = ws + WS_FB_AS;   // 100k
        float* fb_ad  = ws + WS_ADST;
        k_probe0 <<<dim3(1), blk, 0, stream>>>(x, ei, flags, bcnt);
        k_feat1  <<<grdN, blk, 0, stream>>>(x, W1, a1s, a1d, flags, fb_h, fb_as, fb_ad);
        k_selfinit<<<grdO, blk, 0, stream>>>(fb_as, fb_ad, fb_h, fb_den, fb_acc);
        k_edge   <<<grdE, blk, 0, stream>>>(ei, flags, fb_as, fb_ad, fb_h, fb_den, fb_acc);
        k_div_elu<<<grdO, blk, 0, stream>>>(fb_acc, fb_den, b1, flags);
        k_mid    <<<grdN, blk, 0, stream>>>(fb_acc, W2, a2s, a2d, flags, fb_h, fb_as, fb_ad);
        k_selfinit<<<grdO, blk, 0, stream>>>(fb_as, fb_ad, fb_h, fb_den, fb_acc);
        k_edge   <<<grdE, blk, 0, stream>>>(ei, flags, fb_as, fb_ad, fb_h, fb_den, fb_acc);
        k_out    <<<grdO, blk, 0, stream>>>(fb_acc, fb_den, b2, flags, out);
    } else {
        k_diag<<<grdO, blk, 0, stream>>>(out, (float)(ws_size >> 10));
    }
}